// Round 9
// baseline (15943.549 us; speedup 1.0000x reference)
//
#include <hip/hip_runtime.h>

// ACT RNN, T=8192, IO=32, H=256, M=4, EPS=0.01. All f32 in/out.
// Round 9: restructured act_chain.
//  (a) Halting dot with NO LDS round-trip: each lane computes a 4-elem
//      wh-slice partial from the float4 it already loads for the matvec;
//      6-DPP butterfly + readlane(63) gives every lane the bitwise-identical
//      full dot -> uniform branch, no barrier, no plds.
//  (b) Linearity: Ws·h = sum_n w_n * (Ws·s_{n+1}) -> accumulate Wsh from each
//      matvec's z output; ponder step 0 of each timestep needs NO matvec and
//      h never goes to LDS. Per timestep (typical): 2 matvecs, 2 barriers.
//  (c) __launch_bounds__(512, 1): grid is 1 block (8 waves = 2/SIMD anyway),
//      budget 512 VGPRs -> stop the allocator AGPR-parking the 128-VGPR tile
//      (rounds 6-8: VGPR_Count 60/108/112 < tile size = parked = VALU bloat).
// ws = 8.45 MB (AccS aliases U in place; ws_size 16 MiB).

#define T_  8192
#define IO_ 32
#define H_  256

typedef __attribute__((ext_vector_type(2))) float v2f;

template<int CTRL>
__device__ __forceinline__ float dpp_addf(float x) {
    int xi = __builtin_bit_cast(int, x);
    int d = __builtin_amdgcn_update_dpp(xi, xi, CTRL, 0xF, 0xF, false);
    return x + __builtin_bit_cast(float, d);
}

// ---------------- k_prep: WxpT[io][h] = (Wx[:,:H]@Wp)^T, c = Wx[:,:H]@bp + b
__global__ void k_prep(const float* __restrict__ Wx,
                       const float* __restrict__ Wp,
                       const float* __restrict__ bp,
                       const float* __restrict__ b,
                       float* __restrict__ WxpT, float* __restrict__ cvec) {
    int h = blockIdx.x;           // 0..255
    int t = threadIdx.x;          // 0..63
    __shared__ float wxrow[H_];
    for (int j = t; j < H_; j += 64) wxrow[j] = Wx[h * (H_ + 1) + j];
    __syncthreads();
    if (t < IO_) {
        float acc = 0.0f;
        for (int j = 0; j < H_; ++j) acc += wxrow[j] * Wp[j * IO_ + t];
        WxpT[t * H_ + h] = acc;
    } else if (t == IO_) {
        float acc = b[h];
        for (int j = 0; j < H_; ++j) acc += wxrow[j] * bp[j];
        cvec[h] = acc;
    }
}

// ---------------- k_u: U[t][h] = WxpT^T x_t + c  (f32) ----------------
__global__ void k_u(const float* __restrict__ x,
                    const float* __restrict__ WxpT,
                    const float* __restrict__ cvec,
                    float* __restrict__ U) {
    int t0 = blockIdx.x * 8;
    int tid = threadIdx.x;        // 256
    __shared__ float xsf[8 * IO_];
    xsf[tid] = x[(size_t)t0 * IO_ + tid];
    __syncthreads();
    int h = tid;
    float base = cvec[h];
    for (int tt = 0; tt < 8; ++tt) {
        float acc = base;
        #pragma unroll
        for (int io = 0; io < IO_; ++io)
            acc += WxpT[io * H_ + h] * xsf[tt * IO_ + io];
        U[(size_t)(t0 + tt) * H_ + h] = acc;
    }
}

// ---------------- act_chain ----------------
// 512 threads / 8 waves. Lane (w, rg=l>>2, c=l&3): rows rowbase,rowbase+1
// (rowbase = w*32+rg*2) x s-cols [c*64,+64) of Ws (128 VGPRs). s in LDS,
// chunk c at float offset c*68. UAcc: in U[t], out acc_s[t] in place.
__global__ __launch_bounds__(512, 1) void act_chain(
    const float* __restrict__ Ws,
    const float* __restrict__ Wx,
    const float* __restrict__ wh,
    const float* __restrict__ bh1,
    const float* __restrict__ h0,
    float* __restrict__ UAcc,
    float* __restrict__ cumArr,
    float* __restrict__ pc_out)
{
    __shared__ __align__(16) float sbuf[2][4 * 68];

    const int tid = threadIdx.x;
    const int l   = tid & 63;
    const int w   = tid >> 6;        // wave 0..7
    const int rg  = l >> 2;          // 0..15
    const int c   = l & 3;           // 0..3
    const int rowbase = w * 32 + rg * 2;
    const int schunk  = rowbase >> 6;
    const int soff    = rowbase & 63;

    // Ws tile: 2 rows x 64 cols as v2f[2][32] = 128 VGPRs
    v2f wt[2][32];
    #pragma unroll
    for (int r = 0; r < 2; ++r) {
        const float4* src = (const float4*)(Ws + (size_t)(rowbase + r) * H_ + c * 64);
        #pragma unroll
        for (int q = 0; q < 16; ++q) {
            float4 f = src[q];
            wt[r][2 * q]     = (v2f){f.x, f.y};
            wt[r][2 * q + 1] = (v2f){f.z, f.w};
        }
    }
    // wh slice: 4 elems at s-index c*64 + rg*4 (the float4 this lane loads)
    v2f whs0, whs1;
    {
        const float4 f = *(const float4*)(wh + c * 64 + rg * 4);
        whs0 = (v2f){f.x, f.y};
        whs1 = (v2f){f.z, f.w};
    }
    v2f wl2;
    wl2.x = Wx[(size_t)rowbase * (H_ + 1) + H_];
    wl2.y = Wx[(size_t)(rowbase + 1) * (H_ + 1) + H_];
    const float bhf = bh1[0];
    const float thresh = 1.0f - 0.01f;
    const float L2E  = 1.4426950408889634f;
    const float L2E2 = 2.8853900817779268f;

    if (tid < H_) sbuf[0][(tid >> 6) * 68 + (tid & 63)] = h0[tid];
    __syncthreads();

    int cur = 0;
    float pc = 0.0f;

    // ---- prime: Wsh = (Ws·h0) for this lane's 2 rows ----
    v2f Wsh;
    {
        const float4* sp = (const float4*)(&sbuf[cur][c * 68]);
        v2f a0 = {0.f, 0.f}, a1 = {0.f, 0.f};
        #pragma unroll
        for (int q = 0; q < 16; ++q) {
            float4 f = sp[q];
            v2f sa = (v2f){f.x, f.y}, sb = (v2f){f.z, f.w};
            a0 = a0 + wt[0][2 * q] * sa + wt[0][2 * q + 1] * sb;
            a1 = a1 + wt[1][2 * q] * sa + wt[1][2 * q + 1] * sb;
        }
        float y0 = a0.x + a0.y, y1 = a1.x + a1.y;
        y0 = dpp_addf<0xB1>(y0); y0 = dpp_addf<0x4E>(y0);
        y1 = dpp_addf<0xB1>(y1); y1 = dpp_addf<0x4E>(y1);
        Wsh = (v2f){y0, y1};
    }

    #pragma unroll 1
    for (int tg = 0; tg < T_ / 4; ++tg) {
        v2f un[4];
        #pragma unroll
        for (int k = 0; k < 4; ++k)
            un[k] = *(const v2f*)(UAcc + (size_t)(tg * 4 + k) * H_ + rowbase);

        v2f   av[4];
        float cu4[4];

        #pragma unroll
        for (int k4 = 0; k4 < 4; ++k4) {
            const v2f uu = un[k4];

            // ---- ponder step 0: no matvec (a = u + flag + Ws·h) ----
            v2f a = uu + wl2 + Wsh;
            float e0 = __builtin_amdgcn_exp2f(a.x * L2E2);
            float e1 = __builtin_amdgcn_exp2f(a.y * L2E2);
            v2f sprev;
            sprev.x = __builtin_fmaf(-2.0f, __builtin_amdgcn_rcpf(e0 + 1.0f), 1.0f);
            sprev.y = __builtin_fmaf(-2.0f, __builtin_amdgcn_rcpf(e1 + 1.0f), 1.0f);
            if (c == 0) *(v2f*)(&sbuf[cur ^ 1][schunk * 68 + soff]) = sprev;
            cur ^= 1;

            v2f accs = {0.f, 0.f};
            v2f WshN = {0.f, 0.f};
            float cum = 0.0f, nup = 1.0f, remt;
            __syncthreads();

            // ---- matvec steps k = 1.. (z_k and p_{k-1} together) ----
            for (int k = 1; ; ++k) {
                const float4* sp = (const float4*)(&sbuf[cur][c * 68]);
                v2f a0 = {0.f, 0.f}, a1 = {0.f, 0.f};
                v2f pp = {0.f, 0.f};
                #pragma unroll
                for (int q = 0; q < 16; ++q) {
                    float4 f = sp[q];
                    v2f sa = (v2f){f.x, f.y}, sb = (v2f){f.z, f.w};
                    a0 = a0 + wt[0][2 * q] * sa + wt[0][2 * q + 1] * sb;
                    a1 = a1 + wt[1][2 * q] * sa + wt[1][2 * q + 1] * sb;
                    if (q == rg) { pp = pp + whs0 * sa + whs1 * sb; }
                }
                float y0 = a0.x + a0.y, y1 = a1.x + a1.y;
                y0 = dpp_addf<0xB1>(y0); y0 = dpp_addf<0x4E>(y0);
                y1 = dpp_addf<0xB1>(y1); y1 = dpp_addf<0x4E>(y1);
                v2f z = (v2f){y0, y1};

                // full wh·s_k: 64 distinct 4-elem slices -> butterfly
                float pr = pp.x + pp.y;
                pr = dpp_addf<0xB1>(pr);   // xor1 (c)
                pr = dpp_addf<0x4E>(pr);   // xor2 (c)
                pr = dpp_addf<0x124>(pr);  // row_ror:4  (rg within 16-row)
                pr = dpp_addf<0x128>(pr);  // row_ror:8
                pr = dpp_addf<0x142>(pr);  // row_bcast15
                pr = dpp_addf<0x143>(pr);  // row_bcast31 -> lane63 = total
                float dot = __builtin_bit_cast(float,
                    __builtin_amdgcn_readlane(__builtin_bit_cast(int, pr), 63));

                float p = __builtin_amdgcn_rcpf(
                    1.0f + __builtin_amdgcn_exp2f(-(dot + bhf) * L2E));
                bool halt = (cum + p > thresh) || (k == 4);
                float hw = 1.0f - cum;
                float wn = halt ? hw : p;
                accs = accs + wn * sprev;   // w_{k-1} * s_k (own rows)
                WshN = WshN + wn * z;       // w_{k-1} * (Ws·s_k)
                cum += wn;
                if (halt) { remt = hw; break; }

                // continue: s_{k+1} = tanh(u + z)
                v2f an = uu + z;
                float f0 = __builtin_amdgcn_exp2f(an.x * L2E2);
                float f1 = __builtin_amdgcn_exp2f(an.y * L2E2);
                sprev.x = __builtin_fmaf(-2.0f, __builtin_amdgcn_rcpf(f0 + 1.0f), 1.0f);
                sprev.y = __builtin_fmaf(-2.0f, __builtin_amdgcn_rcpf(f1 + 1.0f), 1.0f);
                nup += 1.0f;
                if (c == 0) *(v2f*)(&sbuf[cur ^ 1][schunk * 68 + soff]) = sprev;
                cur ^= 1;
                __syncthreads();
            }

            pc = (pc + nup + remt) * (1.0f / (float)T_);
            av[k4]  = accs;     // h_{t+1} = acc_s
            cu4[k4] = cum;
            Wsh = WshN;         // Ws·h_{t+1}, ready for next step 0
        }

        if (c == 0) {
            #pragma unroll
            for (int k = 0; k < 4; ++k)
                *(v2f*)(UAcc + (size_t)(tg * 4 + k) * H_ + rowbase) = av[k];
        }
        if (tid == 0) {
            #pragma unroll
            for (int k = 0; k < 4; ++k) cumArr[tg * 4 + k] = cu4[k];
        }
    }
    if (tid == 0) pc_out[0] = pc;
}

// ---------------- k_out: ys[t] = Wo@acc_s[t] + cum[t]*bo ----------------
__global__ void k_out(const float* __restrict__ AccS,
                      const float* __restrict__ Wo,
                      const float* __restrict__ bo,
                      const float* __restrict__ cumArr,
                      float* __restrict__ ys) {
    int t0 = blockIdx.x * 8;
    int tid = threadIdx.x;   // 256
    __shared__ float wo[IO_ * 257];
    __shared__ float as[8 * 260];
    for (int i = tid; i < IO_ * H_; i += 256) {
        int o = i / H_, h = i % H_;
        wo[o * 257 + h] = Wo[i];
    }
    for (int i = tid; i < 8 * H_; i += 256) {
        int tt = i / H_, h = i % H_;
        as[tt * 260 + h] = AccS[(size_t)t0 * H_ + i];
    }
    __syncthreads();
    int tt = tid >> 5, o = tid & 31;
    float acc = cumArr[t0 + tt] * bo[o];
    #pragma unroll 4
    for (int h = 0; h < H_; ++h) acc += wo[o * 257 + h] * as[tt * 260 + h];
    ys[(size_t)(t0 + tt) * IO_ + o] = acc;
}

extern "C" void kernel_launch(void* const* d_in, const int* in_sizes, int n_in,
                              void* d_out, int out_size, void* d_ws, size_t ws_size,
                              hipStream_t stream) {
    const float* x  = (const float*)d_in[0];
    const float* h0 = (const float*)d_in[1];
    const float* Wp = (const float*)d_in[2];
    const float* bp = (const float*)d_in[3];
    const float* Wx = (const float*)d_in[4];
    const float* Ws = (const float*)d_in[5];
    const float* b  = (const float*)d_in[6];
    const float* wh = (const float*)d_in[7];
    const float* bh = (const float*)d_in[8];
    const float* Wo = (const float*)d_in[9];
    const float* bo = (const float*)d_in[10];
    float* out = (float*)d_out;   // f32: ys[8192*32] then pc

    char* ws = (char*)d_ws;
    float* WxpT = (float*)ws;                                    //  32 KB
    float* cvec = (float*)(ws + 32768);                          //   1 KB
    float* cumA = (float*)(ws + 33792);                          //  32 KB
    float* UAcc = (float*)(ws + 66560);                          //   8 MB f32
    // total ws use: 8.45 MB (AccS aliases UAcc in place)

    k_prep<<<H_, 64, 0, stream>>>(Wx, Wp, bp, b, WxpT, cvec);
    k_u<<<T_ / 8, 256, 0, stream>>>(x, WxpT, cvec, UAcc);
    act_chain<<<1, 512, 0, stream>>>(Ws, Wx, wh, bh, h0, UAcc, cumA,
                                     out + (size_t)T_ * IO_);
    k_out<<<T_ / 8, 256, 0, stream>>>(UAcc, Wo, bo, cumA, out);
}

// Round 10
// 12188.655 us; speedup vs baseline: 1.3081x; 1.3081x over previous
//
#include <hip/hip_runtime.h>

// ACT RNN, T=8192, IO=32, H=256, M=4, EPS=0.01. All f32 in/out.
// Round 10 = round 8 (best: 12.1 ms) + ONE change: pin the 128-float Ws tile
// into arch VGPRs with empty asm "+v" constraints each timestep-group.
// Rounds 6-9 showed VGPR_Count 60/108/112/96 < tile size => allocator parks
// the tile in AGPRs and pays v_accvgpr_read per element per ponder-iter
// (~550 of the ~1100 VALU-busy cyc/iter). launch_bounds budget didn't stop
// it (round 9, (512,1), still 96); the register-class constraint should.
// ws = 8.45 MB (AccS aliases U in place; ws_size 16 MiB).

#define T_  8192
#define IO_ 32
#define H_  256

typedef __attribute__((ext_vector_type(2))) float v2f;

__device__ __forceinline__ void pin_v(v2f& x) {
    __asm__ __volatile__("" : "+v"(x));
}

template<int CTRL>
__device__ __forceinline__ float dpp_addf(float x) {
    int xi = __builtin_bit_cast(int, x);
    int d = __builtin_amdgcn_update_dpp(xi, xi, CTRL, 0xF, 0xF, false);
    return x + __builtin_bit_cast(float, d);
}

// ---------------- k_prep: WxpT[io][h] = (Wx[:,:H]@Wp)^T, c = Wx[:,:H]@bp + b
__global__ void k_prep(const float* __restrict__ Wx,
                       const float* __restrict__ Wp,
                       const float* __restrict__ bp,
                       const float* __restrict__ b,
                       float* __restrict__ WxpT, float* __restrict__ cvec) {
    int h = blockIdx.x;           // 0..255
    int t = threadIdx.x;          // 0..63
    __shared__ float wxrow[H_];
    for (int j = t; j < H_; j += 64) wxrow[j] = Wx[h * (H_ + 1) + j];
    __syncthreads();
    if (t < IO_) {
        float acc = 0.0f;
        for (int j = 0; j < H_; ++j) acc += wxrow[j] * Wp[j * IO_ + t];
        WxpT[t * H_ + h] = acc;
    } else if (t == IO_) {
        float acc = b[h];
        for (int j = 0; j < H_; ++j) acc += wxrow[j] * bp[j];
        cvec[h] = acc;
    }
}

// ---------------- k_u: U[t][h] = WxpT^T x_t + c  (f32) ----------------
__global__ void k_u(const float* __restrict__ x,
                    const float* __restrict__ WxpT,
                    const float* __restrict__ cvec,
                    float* __restrict__ U) {
    int t0 = blockIdx.x * 8;
    int tid = threadIdx.x;        // 256
    __shared__ float xsf[8 * IO_];
    xsf[tid] = x[(size_t)t0 * IO_ + tid];
    __syncthreads();
    int h = tid;
    float base = cvec[h];
    for (int tt = 0; tt < 8; ++tt) {
        float acc = base;
        #pragma unroll
        for (int io = 0; io < IO_; ++io)
            acc += WxpT[io * H_ + h] * xsf[tt * IO_ + io];
        U[(size_t)(t0 + tt) * H_ + h] = acc;
    }
}

// ---------------- act_chain ----------------
// 512 threads / 8 waves. Lane (w, rg=l>>2, c=l&3): rows rowbase, rowbase+1
// (rowbase = w*32 + rg*2) x s-cols [c*64, c*64+64) of Ws as 64 v2f (128 VGPR,
// asm-pinned to arch VGPRs). s in LDS, chunk c at float offset c*68.
// UAcc: in U[t][h], out AccS[t][h] in place.
__global__ __launch_bounds__(512, 1) void act_chain(
    const float* __restrict__ Ws,
    const float* __restrict__ Wx,
    const float* __restrict__ wh,
    const float* __restrict__ bh1,
    const float* __restrict__ h0,
    float* __restrict__ UAcc,
    float* __restrict__ cumArr,
    float* __restrict__ pc_out)
{
    __shared__ __align__(16) float sbuf[2][4 * 68];
    __shared__ __align__(16) float plds[2][8];

    const int tid = threadIdx.x;
    const int w   = tid >> 6;        // wave 0..7
    const int l   = tid & 63;
    const int rg  = l >> 2;          // row-group 0..15 (2 rows each)
    const int c   = l & 3;           // 64-col chunk 0..3
    const int rowbase = w * 32 + rg * 2;
    const int schunk  = rowbase >> 6;
    const int soff    = rowbase & 63;

    // Ws tile: 2 rows x 64 cols as v2f[2][32] = 128 VGPRs
    v2f wt[2][32];
    #pragma unroll
    for (int r = 0; r < 2; ++r) {
        const float4* src = (const float4*)(Ws + (size_t)(rowbase + r) * H_ + c * 64);
        #pragma unroll
        for (int q = 0; q < 16; ++q) {
            float4 f = src[q];
            wt[r][2 * q]     = (v2f){f.x, f.y};
            wt[r][2 * q + 1] = (v2f){f.z, f.w};
        }
    }

    v2f wl2, whv2;
    wl2.x  = Wx[(size_t)rowbase * (H_ + 1) + H_];
    wl2.y  = Wx[(size_t)(rowbase + 1) * (H_ + 1) + H_];
    whv2.x = wh[rowbase];
    whv2.y = wh[rowbase + 1];
    const float bhf = bh1[0];
    const float thresh = 1.0f - 0.01f;
    const float L2E  = 1.4426950408889634f;   // log2(e)
    const float L2E2 = 2.8853900817779268f;   // 2*log2(e)

    if (tid < H_) sbuf[0][(tid >> 6) * 68 + (tid & 63)] = h0[tid];
    __syncthreads();

    int cur = 0, pp = 0;
    float pc = 0.0f;

    #pragma unroll 1
    for (int tg = 0; tg < T_ / 4; ++tg) {
        // keep the tile in arch VGPRs (defeat AGPR parking)
        #pragma unroll
        for (int r = 0; r < 2; ++r)
            #pragma unroll
            for (int q = 0; q < 32; ++q) pin_v(wt[r][q]);

        v2f un[4];
        #pragma unroll
        for (int k = 0; k < 4; ++k)
            un[k] = *(const v2f*)(UAcc + (size_t)(tg * 4 + k) * H_ + rowbase);

        v2f   av[4];
        float cu4[4];

        #pragma unroll
        for (int k = 0; k < 4; ++k) {
            const v2f uu1 = un[k];
            const v2f uu0 = uu1 + wl2;      // n==0: first-step flag folded in

            v2f accs = {0.f, 0.f};
            float cum = 0.0f, nup = 0.0f, remt = 0.0f;
            float sn0, sn1;

            #pragma unroll 1
            for (int n = 0; n < 4; ++n) {
                // dot: 2 rows x 64 cols, v_pk_fma_f32
                v2f acc0 = {0.f, 0.f}, acc1 = {0.f, 0.f};
                const float4* sp = (const float4*)(&sbuf[cur][c * 68]);
                #pragma unroll
                for (int q = 0; q < 16; ++q) {
                    float4 f = sp[q];
                    v2f sa = (v2f){f.x, f.y};
                    v2f sb = (v2f){f.z, f.w};
                    acc0 = acc0 + wt[0][2 * q] * sa;
                    acc0 = acc0 + wt[0][2 * q + 1] * sb;
                    acc1 = acc1 + wt[1][2 * q] * sa;
                    acc1 = acc1 + wt[1][2 * q + 1] * sb;
                }
                float y0 = acc0.x + acc0.y;
                float y1 = acc1.x + acc1.y;
                // reduce over the 4 c-lanes (quad): xor1, xor2
                y0 = dpp_addf<0xB1>(y0); y0 = dpp_addf<0x4E>(y0);
                y1 = dpp_addf<0xB1>(y1); y1 = dpp_addf<0x4E>(y1);

                v2f uu = (n == 0) ? uu0 : uu1;
                float yy0 = y0 + uu.x;
                float yy1 = y1 + uu.y;
                float e0 = __builtin_amdgcn_exp2f(yy0 * L2E2);
                float e1 = __builtin_amdgcn_exp2f(yy1 * L2E2);
                sn0 = __builtin_fmaf(-2.0f, __builtin_amdgcn_rcpf(e0 + 1.0f), 1.0f);
                sn1 = __builtin_fmaf(-2.0f, __builtin_amdgcn_rcpf(e1 + 1.0f), 1.0f);

                int nxt = cur ^ 1;
                if (c == 0)
                    *(v2f*)(&sbuf[nxt][schunk * 68 + soff]) = (v2f){sn0, sn1};

                // halting partial: quad-uniform; sum rg over row (ror4+ror8),
                // then cross-row (bcast15+bcast31) -> lane63 = wave total
                float part = __builtin_fmaf(whv2.x, sn0, whv2.y * sn1);
                part = dpp_addf<0x124>(part);   // row_ror:4
                part = dpp_addf<0x128>(part);   // row_ror:8
                part = dpp_addf<0x142>(part);   // row_bcast15
                part = dpp_addf<0x143>(part);   // row_bcast31
                if (l == 63) plds[pp][w] = part;
                __syncthreads();

                float4 pa = *(const float4*)(&plds[pp][0]);
                float4 pb = *(const float4*)(&plds[pp][4]);
                float dot = ((pa.x + pa.y) + (pa.z + pa.w)) +
                            ((pb.x + pb.y) + (pb.z + pb.w));
                pp ^= 1;
                float p = __builtin_amdgcn_rcpf(
                    1.0f + __builtin_amdgcn_exp2f(-(dot + bhf) * L2E));
                bool halt = (cum + p > thresh) || (n == 3);
                float hw = 1.0f - cum;
                float wn = halt ? hw : p;
                accs = accs + wn * (v2f){sn0, sn1};
                nup += 1.0f;
                cum += wn;
                if (halt) { remt = hw; break; }   // exact: w==0 afterwards
                cur = nxt;
            }

            pc = (pc + nup + remt) * (1.0f / (float)T_);

            int hb = cur ^ 1;   // dead buffer -> becomes h
            av[k]  = accs;
            cu4[k] = cum;
            if (c == 0)
                *(v2f*)(&sbuf[hb][schunk * 68 + soff]) = accs;
            cur = hb;
            __syncthreads();
        }

        // batched stores: acc_s in place over dead U rows, + cum
        if (c == 0) {
            #pragma unroll
            for (int k = 0; k < 4; ++k)
                *(v2f*)(UAcc + (size_t)(tg * 4 + k) * H_ + rowbase) = av[k];
        }
        if (tid == 0) {
            #pragma unroll
            for (int k = 0; k < 4; ++k) cumArr[tg * 4 + k] = cu4[k];
        }
    }
    if (tid == 0) pc_out[0] = pc;
}

// ---------------- k_out: ys[t] = Wo@acc_s[t] + cum[t]*bo ----------------
__global__ void k_out(const float* __restrict__ AccS,
                      const float* __restrict__ Wo,
                      const float* __restrict__ bo,
                      const float* __restrict__ cumArr,
                      float* __restrict__ ys) {
    int t0 = blockIdx.x * 8;
    int tid = threadIdx.x;   // 256
    __shared__ float wo[IO_ * 257];
    __shared__ float as[8 * 260];
    for (int i = tid; i < IO_ * H_; i += 256) {
        int o = i / H_, h = i % H_;
        wo[o * 257 + h] = Wo[i];
    }
    for (int i = tid; i < 8 * H_; i += 256) {
        int tt = i / H_, h = i % H_;
        as[tt * 260 + h] = AccS[(size_t)t0 * H_ + i];
    }
    __syncthreads();
    int tt = tid >> 5, o = tid & 31;
    float acc = cumArr[t0 + tt] * bo[o];
    #pragma unroll 4
    for (int h = 0; h < H_; ++h) acc += wo[o * 257 + h] * as[tt * 260 + h];
    ys[(size_t)(t0 + tt) * IO_ + o] = acc;
}

extern "C" void kernel_launch(void* const* d_in, const int* in_sizes, int n_in,
                              void* d_out, int out_size, void* d_ws, size_t ws_size,
                              hipStream_t stream) {
    const float* x  = (const float*)d_in[0];
    const float* h0 = (const float*)d_in[1];
    const float* Wp = (const float*)d_in[2];
    const float* bp = (const float*)d_in[3];
    const float* Wx = (const float*)d_in[4];
    const float* Ws = (const float*)d_in[5];
    const float* b  = (const float*)d_in[6];
    const float* wh = (const float*)d_in[7];
    const float* bh = (const float*)d_in[8];
    const float* Wo = (const float*)d_in[9];
    const float* bo = (const float*)d_in[10];
    float* out = (float*)d_out;   // f32: ys[8192*32] then pc

    char* ws = (char*)d_ws;
    float* WxpT = (float*)ws;                                    //  32 KB
    float* cvec = (float*)(ws + 32768);                          //   1 KB
    float* cumA = (float*)(ws + 33792);                          //  32 KB
    float* UAcc = (float*)(ws + 66560);                          //   8 MB f32
    // total ws use: 8.45 MB (AccS aliases UAcc in place)

    k_prep<<<H_, 64, 0, stream>>>(Wx, Wp, bp, b, WxpT, cvec);
    k_u<<<T_ / 8, 256, 0, stream>>>(x, WxpT, cvec, UAcc);
    act_chain<<<1, 512, 0, stream>>>(Ws, Wx, wh, bh, h0, UAcc, cumA,
                                     out + (size_t)T_ * IO_);
    k_out<<<T_ / 8, 256, 0, stream>>>(UAcc, Wo, bo, cumA, out);
}